// Round 3
// baseline (322.232 us; speedup 1.0000x reference)
//
#include <hip/hip_runtime.h>
#include <hip/hip_cooperative_groups.h>
#include <stdint.h>

namespace cg = cooperative_groups;

// Problem shape (fixed by setup_inputs): B=16, C=64, H=128, W=128, fp32 throughout
#define CCH   64
#define HWSZ  16384          // H*W = 2^14
#define BATCH 16
#define NBLK  (BATCH * CCH)  // 1024 blocks, one per contiguous (b,c) slab
#define NPC   (BATCH * HWSZ) // elements per channel = 262144

static constexpr float COS_RY = 0.99500416527802576610f; // cos(0.1)
static constexpr float EPS    = 1e-6f;

__device__ __forceinline__ float qpix(float x) {
    // z = cos(0.1)*cos(x); q = z + z^2 + z^3 + z^4
    float z = COS_RY * __cosf(x);
    return z * (1.0f + z * (1.0f + z * (1.0f + z)));
}

// Single fused cooperative kernel.
// Phase 1: block blk=(b*C+c) reads its 16384-float slab, computes sum(q), sum(q^2),
//          stores per-block partials to ws (agent-scope stores; no init needed).
// grid.sync()
// Phase 2: reduce the 16 batch-partials for channel c, compute scale/shift,
//          re-read the slab (L2-resident) and write y = relu(norm(q))+x.
__global__ __launch_bounds__(256, 4) void fused_kernel(
        const float* __restrict__ x,
        const float* __restrict__ gamma,
        const float* __restrict__ beta,
        float* __restrict__ ps,    // [NBLK] sum(q) per block
        float* __restrict__ ps2,   // [NBLK] sum(q^2) per block
        float* __restrict__ out) {
    const int blk = blockIdx.x;          // b*CCH + c
    const int c   = blk & (CCH - 1);
    const int tid = threadIdx.x;
    const float4* __restrict__ p = (const float4*)(x + (size_t)blk * HWSZ);

    float s = 0.0f, s2 = 0.0f;
    #pragma unroll
    for (int it = 0; it < 16; ++it) {   // 16384 / (256*4) = 16
        const float4 v = p[it * 256 + tid];
        const float q0 = qpix(v.x), q1 = qpix(v.y);
        const float q2 = qpix(v.z), q3 = qpix(v.w);
        s  += (q0 + q1) + (q2 + q3);
        s2 += (q0 * q0 + q1 * q1) + (q2 * q2 + q3 * q3);
    }
    // wave-64 shuffle reduce, then cross-wave via LDS
    #pragma unroll
    for (int off = 32; off > 0; off >>= 1) {
        s  += __shfl_down(s,  off, 64);
        s2 += __shfl_down(s2, off, 64);
    }
    __shared__ float ls[4], ls2[4];
    __shared__ float redc[2];   // broadcast scale/shift
    __shared__ float rb[16], rb2[16];
    const int wave = tid >> 6, lane = tid & 63;
    if (lane == 0) { ls[wave] = s; ls2[wave] = s2; }
    __syncthreads();
    if (tid == 0) {
        const float ts  = (ls[0]  + ls[1])  + (ls[2]  + ls[3]);
        const float ts2 = (ls2[0] + ls2[1]) + (ls2[2] + ls2[3]);
        // agent-scope stores: visible across XCDs after the grid barrier
        __hip_atomic_store(&ps[blk],  ts,  __ATOMIC_RELAXED, __HIP_MEMORY_SCOPE_AGENT);
        __hip_atomic_store(&ps2[blk], ts2, __ATOMIC_RELAXED, __HIP_MEMORY_SCOPE_AGENT);
    }
    __threadfence();            // device-scope release before the grid barrier
    cg::this_grid().sync();

    // gather the 16 batch partials for this channel (blocks b*CCH + c, b=0..15)
    if (tid < 16) {
        rb[tid]  = __hip_atomic_load(&ps[tid * CCH + c],  __ATOMIC_RELAXED, __HIP_MEMORY_SCOPE_AGENT);
        rb2[tid] = __hip_atomic_load(&ps2[tid * CCH + c], __ATOMIC_RELAXED, __HIP_MEMORY_SCOPE_AGENT);
    }
    __syncthreads();
    if (tid == 0) {
        float ts = 0.0f, ts2 = 0.0f;
        #pragma unroll
        for (int b = 0; b < 16; ++b) { ts += rb[b]; ts2 += rb2[b]; }
        const float invn = 1.0f / (float)NPC;
        const float mean = ts * invn;
        const float var  = ts2 * invn - mean * mean;
        const float inv  = rsqrtf(var + EPS);
        const float sc   = gamma[c] * inv;
        redc[0] = sc;
        redc[1] = beta[c] - mean * sc;
    }
    __syncthreads();
    const float scale = redc[0], shift = redc[1];

    float4* __restrict__ po = (float4*)(out + (size_t)blk * HWSZ);
    #pragma unroll
    for (int it = 0; it < 16; ++it) {
        const float4 v = p[it * 256 + tid];   // L2-resident re-read
        float4 o;
        o.x = fmaxf(qpix(v.x) * scale + shift, 0.0f) + v.x;
        o.y = fmaxf(qpix(v.y) * scale + shift, 0.0f) + v.y;
        o.z = fmaxf(qpix(v.z) * scale + shift, 0.0f) + v.z;
        o.w = fmaxf(qpix(v.w) * scale + shift, 0.0f) + v.w;
        po[it * 256 + tid] = o;
    }
}

// ---- fallback path (round-2 structure) in case cooperative launch is refused ----
__global__ __launch_bounds__(256) void stats_kernel(
        const float* __restrict__ x, float* __restrict__ ws) {
    const int blk = blockIdx.x;
    const int c   = blk & (CCH - 1);
    const float4* p = (const float4*)(x + (size_t)blk * HWSZ);
    float s = 0.0f, s2 = 0.0f;
    #pragma unroll
    for (int it = 0; it < 16; ++it) {
        const float4 v = p[it * 256 + (int)threadIdx.x];
        const float q0 = qpix(v.x), q1 = qpix(v.y);
        const float q2 = qpix(v.z), q3 = qpix(v.w);
        s  += (q0 + q1) + (q2 + q3);
        s2 += (q0 * q0 + q1 * q1) + (q2 * q2 + q3 * q3);
    }
    #pragma unroll
    for (int off = 32; off > 0; off >>= 1) {
        s  += __shfl_down(s,  off, 64);
        s2 += __shfl_down(s2, off, 64);
    }
    __shared__ float ls[4], ls2[4];
    const int wave = threadIdx.x >> 6, lane = threadIdx.x & 63;
    if (lane == 0) { ls[wave] = s; ls2[wave] = s2; }
    __syncthreads();
    if (threadIdx.x == 0) {
        atomicAdd(&ws[c],       (ls[0]  + ls[1])  + (ls[2]  + ls[3]));
        atomicAdd(&ws[CCH + c], (ls2[0] + ls2[1]) + (ls2[2] + ls2[3]));
    }
}

__global__ __launch_bounds__(256) void apply_kernel(
        const float* __restrict__ x, const float* __restrict__ gamma,
        const float* __restrict__ beta, const float* __restrict__ ws,
        float* __restrict__ out) {
    const size_t base = ((size_t)blockIdx.x * 256 + threadIdx.x) * 4;
    const int c = (int)((base >> 14) & (CCH - 1));
    const float invn  = 1.0f / (float)NPC;
    const float mean  = ws[c] * invn;
    const float var   = ws[CCH + c] * invn - mean * mean;
    const float inv   = rsqrtf(var + EPS);
    const float scale = gamma[c] * inv;
    const float shift = beta[c] - mean * scale;
    const float4 v = *(const float4*)(x + base);
    float4 o;
    o.x = fmaxf(qpix(v.x) * scale + shift, 0.0f) + v.x;
    o.y = fmaxf(qpix(v.y) * scale + shift, 0.0f) + v.y;
    o.z = fmaxf(qpix(v.z) * scale + shift, 0.0f) + v.z;
    o.w = fmaxf(qpix(v.w) * scale + shift, 0.0f) + v.w;
    *(float4*)(out + base) = o;
}

extern "C" void kernel_launch(void* const* d_in, const int* in_sizes, int n_in,
                              void* d_out, int out_size, void* d_ws, size_t ws_size,
                              hipStream_t stream) {
    const float* x     = (const float*)d_in[0];
    const float* gamma = (const float*)d_in[1];
    const float* beta  = (const float*)d_in[2];
    float* out = (float*)d_out;
    float* ps  = (float*)d_ws;         // [NBLK]
    float* ps2 = ps + NBLK;            // [NBLK]

    void* args[] = {(void*)&x, (void*)&gamma, (void*)&beta,
                    (void*)&ps, (void*)&ps2, (void*)&out};
    hipError_t err = hipLaunchCooperativeKernel(
        (const void*)fused_kernel, dim3(NBLK), dim3(256), args, 0, stream);

    if (err != hipSuccess) {
        // fallback: round-2 two-kernel path (also capture-safe)
        float* ws = (float*)d_ws;
        hipMemsetAsync(ws, 0, 2 * CCH * sizeof(float), stream);
        stats_kernel<<<NBLK, 256, 0, stream>>>(x, ws);
        apply_kernel<<<(BATCH * CCH * HWSZ / 4) / 256, 256, 0, stream>>>(
            x, gamma, beta, ws, out);
    }
}

// Round 5
// 119.169 us; speedup vs baseline: 2.7040x; 2.7040x over previous
//
#include <hip/hip_runtime.h>
#include <stdint.h>

// Problem shape (fixed by setup_inputs): B=16, C=64, H=128, W=128, fp32 throughout
#define CCH   64
#define HWSZ  16384            // H*W = 2^14
#define BATCH 16
#define NSLAB (BATCH * CCH)    // 1024 contiguous (b,c) slabs of 16384 floats
#define SEGS  4                // stats segments per slab
#define NSEG  (NSLAB * SEGS)   // 4096 stats blocks / partials per moment
#define NPC   (BATCH * HWSZ)   // elements per channel = 262144
#define NTOT  (BATCH * CCH * HWSZ)

static constexpr float COS_RY = 0.99500416527802576610f; // cos(0.1)
static constexpr float EPS    = 1e-6f;

typedef float fvec4 __attribute__((ext_vector_type(4)));  // native vector for nt-store

__device__ __forceinline__ float qpix(float x) {
    // z = cos(0.1)*cos(x); q = z + z^2 + z^3 + z^4
    float z = COS_RY * __cosf(x);
    return z * (1.0f + z * (1.0f + z * (1.0f + z)));
}

// Pass 1: per-(channel,segment) partial sums, plain stores (no memset, no atomics).
// Block blk: slab = blk>>2 (= b*CCH+c), seg = blk&3. Each block covers 4096 floats.
// Partial layout: ps[c*64 + b*4 + seg] so each channel's 64 partials are contiguous.
__global__ __launch_bounds__(256) void stats_kernel(
        const float* __restrict__ x, float* __restrict__ ps) {
    const int blk  = blockIdx.x;          // 0..4095
    const int slab = blk >> 2;            // b*CCH + c
    const int seg  = blk & (SEGS - 1);
    const int c    = slab & (CCH - 1);
    const int b    = slab >> 6;
    const float4* __restrict__ p =
        (const float4*)(x + (size_t)slab * HWSZ + (size_t)seg * 4096);

    float s = 0.0f, s2 = 0.0f;
    #pragma unroll
    for (int it = 0; it < 4; ++it) {      // 4096 / (256*4) = 4
        const float4 v = p[it * 256 + (int)threadIdx.x];
        const float q0 = qpix(v.x), q1 = qpix(v.y);
        const float q2 = qpix(v.z), q3 = qpix(v.w);
        s  += (q0 + q1) + (q2 + q3);
        s2 += (q0 * q0 + q1 * q1) + (q2 * q2 + q3 * q3);
    }
    #pragma unroll
    for (int off = 32; off > 0; off >>= 1) {
        s  += __shfl_down(s,  off, 64);
        s2 += __shfl_down(s2, off, 64);
    }
    __shared__ float ls[4], ls2[4];
    const int wave = threadIdx.x >> 6, lane = threadIdx.x & 63;
    if (lane == 0) { ls[wave] = s; ls2[wave] = s2; }
    __syncthreads();
    if (threadIdx.x == 0) {
        const int idx = c * 64 + b * SEGS + seg;
        ps[idx]        = (ls[0]  + ls[1])  + (ls[2]  + ls[3]);
        ps[NSEG + idx] = (ls2[0] + ls2[1]) + (ls2[2] + ls2[3]);
    }
}

// Pass 2: block = 2048-float channel-uniform tile (8 per slab).
// First wave reduces the channel's 64 partials; all threads then apply
// y = relu((q-mean)*rsqrt(var+eps)*gamma+beta) + x with nontemporal stores.
__global__ __launch_bounds__(256) void apply_kernel(
        const float* __restrict__ x,
        const float* __restrict__ gamma,
        const float* __restrict__ beta,
        const float* __restrict__ ps,
        float* __restrict__ out) {
    const size_t blockBase = (size_t)blockIdx.x * 2048;   // floats
    const int c = (int)((blockBase >> 14) & (CCH - 1));   // uniform per block
    const int tid = threadIdx.x;

    // issue main loads early (independent of the reduction)
    const float4* __restrict__ p = (const float4*)(x + blockBase);
    const float4 v0 = p[tid];
    const float4 v1 = p[256 + tid];

    __shared__ float sh[2];
    if (tid < 64) {
        float a  = ps[c * 64 + tid];
        float a2 = ps[NSEG + c * 64 + tid];
        #pragma unroll
        for (int off = 32; off > 0; off >>= 1) {
            a  += __shfl_down(a,  off, 64);
            a2 += __shfl_down(a2, off, 64);
        }
        if (tid == 0) {
            const float invn = 1.0f / (float)NPC;
            const float mean = a * invn;
            const float var  = a2 * invn - mean * mean;
            const float inv  = rsqrtf(var + EPS);
            const float sc   = gamma[c] * inv;
            sh[0] = sc;
            sh[1] = beta[c] - mean * sc;
        }
    }
    __syncthreads();
    const float scale = sh[0], shift = sh[1];

    fvec4 o0, o1;
    o0.x = fmaxf(qpix(v0.x) * scale + shift, 0.0f) + v0.x;
    o0.y = fmaxf(qpix(v0.y) * scale + shift, 0.0f) + v0.y;
    o0.z = fmaxf(qpix(v0.z) * scale + shift, 0.0f) + v0.z;
    o0.w = fmaxf(qpix(v0.w) * scale + shift, 0.0f) + v0.w;
    o1.x = fmaxf(qpix(v1.x) * scale + shift, 0.0f) + v1.x;
    o1.y = fmaxf(qpix(v1.y) * scale + shift, 0.0f) + v1.y;
    o1.z = fmaxf(qpix(v1.z) * scale + shift, 0.0f) + v1.z;
    o1.w = fmaxf(qpix(v1.w) * scale + shift, 0.0f) + v1.w;

    fvec4* __restrict__ po = (fvec4*)(out + blockBase);
    __builtin_nontemporal_store(o0, &po[tid]);
    __builtin_nontemporal_store(o1, &po[256 + tid]);
}

extern "C" void kernel_launch(void* const* d_in, const int* in_sizes, int n_in,
                              void* d_out, int out_size, void* d_ws, size_t ws_size,
                              hipStream_t stream) {
    const float* x     = (const float*)d_in[0];
    const float* gamma = (const float*)d_in[1];
    const float* beta  = (const float*)d_in[2];
    float* out = (float*)d_out;
    float* ps  = (float*)d_ws;   // 2*NSEG floats = 32 KB, fully overwritten by stats

    stats_kernel<<<NSEG, 256, 0, stream>>>(x, ps);

    const int apply_blocks = NTOT / 2048;   // 8192
    apply_kernel<<<apply_blocks, 256, 0, stream>>>(x, gamma, beta, ps, out);
}